// Round 7
// baseline (147.356 us; speedup 1.0000x reference)
//
#include <hip/hip_runtime.h>
#include <hip/hip_bf16.h>
#include <stdint.h>

#define N_ROWS 8192
#define DIM 512
#define NLAB 512
#define MARGIN_F 0.35f
#define NBLK 64                        // 8192/128 row-blocks
#define NPURE 1953                     // tiles with bi-bj >= 2
#define NDIAG 127                      // diagonal (64) + subdiagonal (63)
#define NTILE (NPURE + NDIAG)          // 2080
#define ROWSTAT_BLOCKS (N_ROWS / 4)    // 2048

typedef __attribute__((ext_vector_type(4))) float floatx4;
typedef __attribute__((ext_vector_type(8))) int intx8;

// order-preserving float->uint map (for atomicMin/Max on floats)
__device__ __forceinline__ unsigned enc_f(float f) {
    unsigned u = __float_as_uint(f);
    return (u & 0x80000000u) ? ~u : (u | 0x80000000u);
}
__device__ __forceinline__ float dec_f(unsigned e) {
    unsigned u = (e & 0x80000000u) ? (e ^ 0x80000000u) : ~e;
    return __uint_as_float(u);
}

__device__ __forceinline__ void load_lds16(const void* g, void* l) {
    __builtin_amdgcn_global_load_lds((__attribute__((address_space(1))) void*)(void*)g,
                                     (__attribute__((address_space(3))) void*)l, 16, 0, 0);
}

// Single block: histogram of labels + exclusive scan -> offsets, zero rank counters + out.
__global__ __launch_bounds__(512) void histscan_kernel(const int* __restrict__ label,
                                                       int* __restrict__ offsetArr,
                                                       int* __restrict__ cnt,
                                                       float* __restrict__ out) {
    __shared__ int h[NLAB];
    __shared__ int sc[NLAB];
    int t = threadIdx.x;
    h[t] = 0;
    __syncthreads();
    for (int i = t; i < N_ROWS; i += 512) atomicAdd(&h[label[i]], 1);
    __syncthreads();
    int v = h[t];
    sc[t] = v;
    __syncthreads();
    for (int d = 1; d < NLAB; d <<= 1) {
        int add = (t >= d) ? sc[t - d] : 0;
        __syncthreads();
        sc[t] += add;
        __syncthreads();
    }
    offsetArr[t] = sc[t] - v;   // exclusive prefix
    cnt[t] = 0;
    if (t == 0) out[0] = 0.f;
}

// One wave per row: CE partial + fp8(e4m3) conversion scattered to label-sorted position.
// Also initializes minEnc/maxEnc.
__global__ __launch_bounds__(256) void rowstats_kernel(const float* __restrict__ x,
                                                       const int* __restrict__ label,
                                                       const int* __restrict__ offsetArr,
                                                       int* __restrict__ cnt,
                                                       unsigned char* __restrict__ a8,
                                                       int* __restrict__ sortedLabel,
                                                       float* __restrict__ cePartial,
                                                       unsigned* __restrict__ minEnc,
                                                       unsigned* __restrict__ maxEnc) {
    int gid = blockIdx.x * 256 + threadIdx.x;
    if (gid < N_ROWS) { minEnc[gid] = 0xFFFFFFFFu; maxEnc[gid] = 0u; }

    int w = threadIdx.x >> 6;
    int row = blockIdx.x * 4 + w;
    int l = threadIdx.x & 63;
    const float* xr = x + (size_t)row * DIM;
    float4 v0 = ((const float4*)xr)[2 * l];
    float4 v1 = ((const float4*)xr)[2 * l + 1];
    float vals[8] = {v0.x, v0.y, v0.z, v0.w, v1.x, v1.y, v1.z, v1.w};

    float mx = vals[0];
#pragma unroll
    for (int i = 1; i < 8; i++) mx = fmaxf(mx, vals[i]);
#pragma unroll
    for (int s = 1; s < 64; s <<= 1) mx = fmaxf(mx, __shfl_xor(mx, s, 64));

    float se = 0.f;
#pragma unroll
    for (int i = 0; i < 8; i++) se += expf(vals[i] - mx);
#pragma unroll
    for (int s = 1; s < 64; s <<= 1) se += __shfl_xor(se, s, 64);

    // sorted position for this row (counting-sort rank)
    int pos = 0;
    if (l == 0) {
        int lab = label[row];
        pos = offsetArr[lab] + atomicAdd(&cnt[lab], 1);
        sortedLabel[pos] = lab;
    }
    pos = __shfl(pos, 0, 64);

    // pack 8 fp8 e4m3 and store 8B to the sorted slot
    int w0 = __builtin_amdgcn_cvt_pk_fp8_f32(vals[0], vals[1], 0, false);
    w0 = __builtin_amdgcn_cvt_pk_fp8_f32(vals[2], vals[3], w0, true);
    int w1 = __builtin_amdgcn_cvt_pk_fp8_f32(vals[4], vals[5], 0, false);
    w1 = __builtin_amdgcn_cvt_pk_fp8_f32(vals[6], vals[7], w1, true);
    ((uint2*)(a8 + (size_t)pos * DIM))[l] = make_uint2((unsigned)w0, (unsigned)w1);

    __shared__ float wsum[4];
    if (l == 0) {
        float tl = xr[label[row]];
        wsum[w] = mx + logf(se) - tl;
    }
    __syncthreads();
    if (threadIdx.x == 0)
        cePartial[blockIdx.x] = wsum[0] + wsum[1] + wsum[2] + wsum[3];
}

// Merged GEMM on fp8: blocks [0, NDIAG) diag/subdiag tiles (mixed epilogue),
// blocks [NDIAG, NTILE) pure tiles (max-only). 128x128 tile, BK=128,
// 16B-granule XOR-swizzled LDS, mfma_scale 16x16x128 f8f6f4 (scale=1.0),
// 2x2 waves x 4x4 frags. launch_bounds(256,4) pins regs at <=128.
// K-loop processes B-fragments in HALVES (live operands ~24 VGPR) so the
// 64-VGPR half of the unified file is not exceeded (round-6 lesson: full
// bfv[4] preload -> scratch spill -> 68 MB HBM writes).
__global__ __launch_bounds__(256, 4) void gemm_kernel(const unsigned char* __restrict__ A,
                                                      const int* __restrict__ sortedLabel,
                                                      unsigned* __restrict__ minEnc,
                                                      unsigned* __restrict__ maxEnc) {
    __shared__ unsigned char As[128 * 128];   // 16 KB
    __shared__ unsigned char Bs[128 * 128];   // 16 KB
    __shared__ float redA[128][2], redB[128][2];   // Imx / Jmx

    int b = blockIdx.x;
    bool diag = (b < NDIAG);
    int bi, bj;
    if (diag) {
        bi = (b < 64) ? b : (b - 63);
        bj = (b < 64) ? b : (b - 64);
    } else {
        int p = b - NDIAG;
        int ci = (int)((sqrtf(8.0f * (float)p + 1.0f) - 1.0f) * 0.5f);
        while ((ci + 1) * (ci + 2) / 2 <= p) ci++;
        while (ci * (ci + 1) / 2 > p) ci--;
        bj = p - ci * (ci + 1) / 2;
        bi = ci + 2;
    }
    int ibase = bi * 128, jbase = bj * 128;

    int t = threadIdx.x;
    int w = t >> 6, l = t & 63;
    int wm = w >> 1, wn = w & 1;
    int q = l >> 4, lm = l & 15;

    floatx4 acc[4][4];
#pragma unroll
    for (int a = 0; a < 4; a++)
#pragma unroll
        for (int c = 0; c < 4; c++) acc[a][c] = (floatx4)0.f;

    // per-lane staging geometry (loop-invariant)
    int s_r = t >> 3;                 // row within tile for this thread's slot
    int s_c = ((t & 7) ^ (s_r & 7));  // swizzled 16B chunk

    for (int kk = 0; kk < 4; kk++) {
        int k0 = kk * 128;
#pragma unroll
        for (int i2 = 0; i2 < 4; i2++) {
            int r = i2 * 32 + s_r;
            int slot = (i2 * 256 + t) * 16;
            load_lds16(A + (size_t)(ibase + r) * DIM + k0 + s_c * 16, As + slot);
            load_lds16(A + (size_t)(jbase + r) * DIM + k0 + s_c * 16, Bs + slot);
        }
        __syncthreads();

#pragma unroll
        for (int half = 0; half < 2; half++) {
            intx8 bfv[2];
#pragma unroll
            for (int h2 = 0; h2 < 2; h2++) {
                int tn = half * 2 + h2;
                int R = wn * 64 + tn * 16 + lm;
                const int4* rowp = (const int4*)(Bs + R * 128);
                int4 lo = rowp[(2 * q) ^ (R & 7)];
                int4 hi = rowp[(2 * q + 1) ^ (R & 7)];
                intx8 v;
                v[0] = lo.x; v[1] = lo.y; v[2] = lo.z; v[3] = lo.w;
                v[4] = hi.x; v[5] = hi.y; v[6] = hi.z; v[7] = hi.w;
                bfv[h2] = v;
            }
#pragma unroll
            for (int tm = 0; tm < 4; tm++) {
                int R = wm * 64 + tm * 16 + lm;
                const int4* rowp = (const int4*)(As + R * 128);
                int4 lo = rowp[(2 * q) ^ (R & 7)];
                int4 hi = rowp[(2 * q + 1) ^ (R & 7)];
                intx8 af;
                af[0] = lo.x; af[1] = lo.y; af[2] = lo.z; af[3] = lo.w;
                af[4] = hi.x; af[5] = hi.y; af[6] = hi.z; af[7] = hi.w;
                acc[tm][half * 2] = __builtin_amdgcn_mfma_scale_f32_16x16x128_f8f6f4(
                    af, bfv[0], acc[tm][half * 2], 0, 0,
                    0, 0x7F7F7F7F, 0, 0x7F7F7F7F);
                acc[tm][half * 2 + 1] = __builtin_amdgcn_mfma_scale_f32_16x16x128_f8f6f4(
                    af, bfv[1], acc[tm][half * 2 + 1], 0, 0,
                    0, 0x7F7F7F7F, 0, 0x7F7F7F7F);
            }
        }
        __syncthreads();
    }

    // C/D layout: col = lane&15, row = (lane>>4)*4 + reg [m89/m91; shape-determined]
    const float INF = __builtin_inff();

    if (!diag) {
        // ---- max-only epilogue (no labels) ----
        float mxJ[4];
#pragma unroll
        for (int tn = 0; tn < 4; tn++) mxJ[tn] = -INF;
#pragma unroll
        for (int tm = 0; tm < 4; tm++) {
#pragma unroll
            for (int r = 0; r < 4; r++) {
                int row_l = wm * 64 + tm * 16 + q * 4 + r;
                float mxI = -INF;
#pragma unroll
                for (int tn = 0; tn < 4; tn++) {
                    float v = acc[tm][tn][r];
                    mxI = fmaxf(mxI, v);
                    mxJ[tn] = fmaxf(mxJ[tn], v);
                }
#pragma unroll
                for (int s = 1; s < 16; s <<= 1)
                    mxI = fmaxf(mxI, __shfl_xor(mxI, s, 64));
                if (lm == 0) redA[row_l][wn] = mxI;
            }
        }
#pragma unroll
        for (int tn = 0; tn < 4; tn++) {
#pragma unroll
            for (int s = 16; s < 64; s <<= 1)
                mxJ[tn] = fmaxf(mxJ[tn], __shfl_xor(mxJ[tn], s, 64));
            if (q == 0) redB[wn * 64 + tn * 16 + lm][wm] = mxJ[tn];
        }
        __syncthreads();
        if (t < 128) {
            atomicMax(&maxEnc[ibase + t], enc_f(fmaxf(redA[t][0], redA[t][1])));
            atomicMax(&maxEnc[jbase + t], enc_f(fmaxf(redB[t][0], redB[t][1])));
        }
    } else {
        // ---- mixed epilogue (min-same / max-diff); extra LDS aliases dead As ----
        int* labi = (int*)As;                             // 512 B
        int* labj = labi + 128;                           // 512 B
        float (*redImn)[2] = (float (*)[2])(labj + 128);  // 1 KB
        float (*redJmn)[2] = redImn + 128;                // 1 KB
        if (t < 128) labi[t] = sortedLabel[ibase + t];
        else labj[t - 128] = sortedLabel[jbase + t - 128];
        __syncthreads();

        int jlab[4];
#pragma unroll
        for (int tn = 0; tn < 4; tn++) jlab[tn] = labj[wn * 64 + tn * 16 + lm];

        float mnJ[4], mxJ[4];
#pragma unroll
        for (int tn = 0; tn < 4; tn++) { mnJ[tn] = INF; mxJ[tn] = -INF; }

#pragma unroll
        for (int tm = 0; tm < 4; tm++) {
#pragma unroll
            for (int r = 0; r < 4; r++) {
                int row_l = wm * 64 + tm * 16 + q * 4 + r;
                int il = labi[row_l];
                float mnI = INF, mxI = -INF;
#pragma unroll
                for (int tn = 0; tn < 4; tn++) {
                    float v = acc[tm][tn][r];
                    bool same = (jlab[tn] == il);
                    float vs = same ? v : INF;
                    float vd = same ? -INF : v;
                    mnI = fminf(mnI, vs);
                    mxI = fmaxf(mxI, vd);
                    mnJ[tn] = fminf(mnJ[tn], vs);
                    mxJ[tn] = fmaxf(mxJ[tn], vd);
                }
#pragma unroll
                for (int s = 1; s < 16; s <<= 1) {
                    mnI = fminf(mnI, __shfl_xor(mnI, s, 64));
                    mxI = fmaxf(mxI, __shfl_xor(mxI, s, 64));
                }
                if (lm == 0) { redImn[row_l][wn] = mnI; redA[row_l][wn] = mxI; }
            }
        }
#pragma unroll
        for (int tn = 0; tn < 4; tn++) {
#pragma unroll
            for (int s = 16; s < 64; s <<= 1) {
                mnJ[tn] = fminf(mnJ[tn], __shfl_xor(mnJ[tn], s, 64));
                mxJ[tn] = fmaxf(mxJ[tn], __shfl_xor(mxJ[tn], s, 64));
            }
            if (q == 0) {
                int col_l = wn * 64 + tn * 16 + lm;
                redJmn[col_l][wm] = mnJ[tn];
                redB[col_l][wm] = mxJ[tn];
            }
        }
        __syncthreads();
        if (t < 128) {
            atomicMin(&minEnc[ibase + t], enc_f(fminf(redImn[t][0], redImn[t][1])));
            atomicMax(&maxEnc[ibase + t], enc_f(fmaxf(redA[t][0], redA[t][1])));
            atomicMin(&minEnc[jbase + t], enc_f(fminf(redJmn[t][0], redJmn[t][1])));
            atomicMax(&maxEnc[jbase + t], enc_f(fmaxf(redB[t][0], redB[t][1])));
        }
    }
}

// 32 blocks; one float atomicAdd per block into pre-zeroed out[0].
__global__ __launch_bounds__(256) void finalize_kernel(const unsigned* __restrict__ minEnc,
                                                       const unsigned* __restrict__ maxEnc,
                                                       const float* __restrict__ cePartial,
                                                       float* __restrict__ out) {
    int gid = blockIdx.x * 256 + threadIdx.x;   // 8192 threads total
    float mn = dec_f(minEnc[gid]);
    float mxv = dec_f(maxEnc[gid]);
    // pos - neg = 2*(max_diff G - min_same G); sq_i cancels, sq_j ≈ 1 (dev ~1e-7)
    float s = fmaxf(2.0f * (mxv - mn) + MARGIN_F, 0.f);
    if (gid < ROWSTAT_BLOCKS) s += cePartial[gid];
#pragma unroll
    for (int sh = 1; sh < 64; sh <<= 1) s += __shfl_xor(s, sh, 64);
    __shared__ float red[4];
    int w = threadIdx.x >> 6, l = threadIdx.x & 63;
    if (l == 0) red[w] = s;
    __syncthreads();
    if (threadIdx.x == 0)
        atomicAdd(out, (red[0] + red[1] + red[2] + red[3]) * (1.0f / (float)N_ROWS));
}

extern "C" void kernel_launch(void* const* d_in, const int* in_sizes, int n_in,
                              void* d_out, int out_size, void* d_ws, size_t ws_size,
                              hipStream_t stream) {
    const float* x = (const float*)d_in[0];
    const int* label = (const int*)d_in[1];
    float* out = (float*)d_out;

    char* ws = (char*)d_ws;
    unsigned char* a8 = (unsigned char*)ws;                      // 4 MB fp8 sorted copy
    char* p = ws + (size_t)N_ROWS * DIM;
    unsigned* minEnc = (unsigned*)p;            p += N_ROWS * 4;
    unsigned* maxEnc = (unsigned*)p;            p += N_ROWS * 4;
    float* cePartial = (float*)p;               p += ROWSTAT_BLOCKS * 4;
    int* offsetArr = (int*)p;                   p += NLAB * 4;
    int* cnt = (int*)p;                         p += NLAB * 4;
    int* sortedLabel = (int*)p;                 p += N_ROWS * 4;

    histscan_kernel<<<1, 512, 0, stream>>>(label, offsetArr, cnt, out);
    rowstats_kernel<<<ROWSTAT_BLOCKS, 256, 0, stream>>>(x, label, offsetArr, cnt, a8,
                                                        sortedLabel, cePartial, minEnc, maxEnc);
    gemm_kernel<<<NTILE, 256, 0, stream>>>(a8, sortedLabel, minEnc, maxEnc);
    finalize_kernel<<<32, 256, 0, stream>>>(minEnc, maxEnc, cePartial, out);
}

// Round 8
// 110.337 us; speedup vs baseline: 1.3355x; 1.3355x over previous
//
#include <hip/hip_runtime.h>
#include <hip/hip_bf16.h>
#include <stdint.h>

#define N_ROWS 8192
#define DIM 512
#define NLAB 512
#define MARGIN_F 0.35f
#define NBLK 64                        // 8192/128 row-blocks
#define NPURE 1953                     // tiles with bi-bj >= 2
#define NDIAG 127                      // diagonal (64) + subdiagonal (63)
#define NTILE (NPURE + NDIAG)          // 2080
#define ROWSTAT_BLOCKS (N_ROWS / 4)    // 2048

typedef __attribute__((ext_vector_type(4))) float floatx4;
typedef __attribute__((ext_vector_type(8))) int intx8;

// order-preserving float->uint map (for atomicMin/Max on floats)
__device__ __forceinline__ unsigned enc_f(float f) {
    unsigned u = __float_as_uint(f);
    return (u & 0x80000000u) ? ~u : (u | 0x80000000u);
}
__device__ __forceinline__ float dec_f(unsigned e) {
    unsigned u = (e & 0x80000000u) ? (e ^ 0x80000000u) : ~e;
    return __uint_as_float(u);
}

__device__ __forceinline__ void load_lds16(const void* g, void* l) {
    __builtin_amdgcn_global_load_lds((__attribute__((address_space(1))) void*)(void*)g,
                                     (__attribute__((address_space(3))) void*)l, 16, 0, 0);
}

// Single block: histogram of labels + exclusive scan -> offsets, zero rank counters + out.
__global__ __launch_bounds__(512) void histscan_kernel(const int* __restrict__ label,
                                                       int* __restrict__ offsetArr,
                                                       int* __restrict__ cnt,
                                                       float* __restrict__ out) {
    __shared__ int h[NLAB];
    __shared__ int sc[NLAB];
    int t = threadIdx.x;
    h[t] = 0;
    __syncthreads();
    for (int i = t; i < N_ROWS; i += 512) atomicAdd(&h[label[i]], 1);
    __syncthreads();
    int v = h[t];
    sc[t] = v;
    __syncthreads();
    for (int d = 1; d < NLAB; d <<= 1) {
        int add = (t >= d) ? sc[t - d] : 0;
        __syncthreads();
        sc[t] += add;
        __syncthreads();
    }
    offsetArr[t] = sc[t] - v;   // exclusive prefix
    cnt[t] = 0;
    if (t == 0) out[0] = 0.f;
}

// One wave per row: CE partial + fp8(e4m3) conversion scattered to label-sorted position.
// Also initializes minEnc/maxEnc.
__global__ __launch_bounds__(256) void rowstats_kernel(const float* __restrict__ x,
                                                       const int* __restrict__ label,
                                                       const int* __restrict__ offsetArr,
                                                       int* __restrict__ cnt,
                                                       unsigned char* __restrict__ a8,
                                                       int* __restrict__ sortedLabel,
                                                       float* __restrict__ cePartial,
                                                       unsigned* __restrict__ minEnc,
                                                       unsigned* __restrict__ maxEnc) {
    int gid = blockIdx.x * 256 + threadIdx.x;
    if (gid < N_ROWS) { minEnc[gid] = 0xFFFFFFFFu; maxEnc[gid] = 0u; }

    int w = threadIdx.x >> 6;
    int row = blockIdx.x * 4 + w;
    int l = threadIdx.x & 63;
    const float* xr = x + (size_t)row * DIM;
    float4 v0 = ((const float4*)xr)[2 * l];
    float4 v1 = ((const float4*)xr)[2 * l + 1];
    float vals[8] = {v0.x, v0.y, v0.z, v0.w, v1.x, v1.y, v1.z, v1.w};

    float mx = vals[0];
#pragma unroll
    for (int i = 1; i < 8; i++) mx = fmaxf(mx, vals[i]);
#pragma unroll
    for (int s = 1; s < 64; s <<= 1) mx = fmaxf(mx, __shfl_xor(mx, s, 64));

    float se = 0.f;
#pragma unroll
    for (int i = 0; i < 8; i++) se += expf(vals[i] - mx);
#pragma unroll
    for (int s = 1; s < 64; s <<= 1) se += __shfl_xor(se, s, 64);

    // sorted position for this row (counting-sort rank)
    int pos = 0;
    if (l == 0) {
        int lab = label[row];
        pos = offsetArr[lab] + atomicAdd(&cnt[lab], 1);
        sortedLabel[pos] = lab;
    }
    pos = __shfl(pos, 0, 64);

    // pack 8 fp8 e4m3 and store 8B to the sorted slot
    int w0 = __builtin_amdgcn_cvt_pk_fp8_f32(vals[0], vals[1], 0, false);
    w0 = __builtin_amdgcn_cvt_pk_fp8_f32(vals[2], vals[3], w0, true);
    int w1 = __builtin_amdgcn_cvt_pk_fp8_f32(vals[4], vals[5], 0, false);
    w1 = __builtin_amdgcn_cvt_pk_fp8_f32(vals[6], vals[7], w1, true);
    ((uint2*)(a8 + (size_t)pos * DIM))[l] = make_uint2((unsigned)w0, (unsigned)w1);

    __shared__ float wsum[4];
    if (l == 0) {
        float tl = xr[label[row]];
        wsum[w] = mx + logf(se) - tl;
    }
    __syncthreads();
    if (threadIdx.x == 0)
        cePartial[blockIdx.x] = wsum[0] + wsum[1] + wsum[2] + wsum[3];
}

// Merged GEMM on fp8: blocks [0, NDIAG) diag/subdiag tiles (mixed epilogue),
// blocks [NDIAG, NTILE) pure tiles (max-only). 128x128 tile, BK=128,
// 16B-granule XOR-swizzled LDS, mfma_scale 16x16x128 f8f6f4 (scale=1.0),
// 2x2 waves x 4x4 frags.
// launch_bounds(256,3): ~168 unified regs/wave. acc owns 64 AGPR; operands
// (bfv[4]=32 + af=8 + staging/temps) need ~70 arch VGPRs. (256,4) pinned the
// arch file at 64 and spilled 68-135 MB to scratch (rounds 6-7 post-mortems).
__global__ __launch_bounds__(256, 3) void gemm_kernel(const unsigned char* __restrict__ A,
                                                      const int* __restrict__ sortedLabel,
                                                      unsigned* __restrict__ minEnc,
                                                      unsigned* __restrict__ maxEnc) {
    __shared__ unsigned char As[128 * 128];   // 16 KB
    __shared__ unsigned char Bs[128 * 128];   // 16 KB
    __shared__ float redA[128][2], redB[128][2];   // Imx / Jmx

    int b = blockIdx.x;
    bool diag = (b < NDIAG);
    int bi, bj;
    if (diag) {
        bi = (b < 64) ? b : (b - 63);
        bj = (b < 64) ? b : (b - 64);
    } else {
        int p = b - NDIAG;
        int ci = (int)((sqrtf(8.0f * (float)p + 1.0f) - 1.0f) * 0.5f);
        while ((ci + 1) * (ci + 2) / 2 <= p) ci++;
        while (ci * (ci + 1) / 2 > p) ci--;
        bj = p - ci * (ci + 1) / 2;
        bi = ci + 2;
    }
    int ibase = bi * 128, jbase = bj * 128;

    int t = threadIdx.x;
    int w = t >> 6, l = t & 63;
    int wm = w >> 1, wn = w & 1;
    int q = l >> 4, lm = l & 15;

    floatx4 acc[4][4];
#pragma unroll
    for (int a = 0; a < 4; a++)
#pragma unroll
        for (int c = 0; c < 4; c++) acc[a][c] = (floatx4)0.f;

    // per-lane staging geometry (loop-invariant)
    int s_r = t >> 3;                 // row within tile for this thread's slot
    int s_c = ((t & 7) ^ (s_r & 7));  // swizzled 16B chunk

    for (int kk = 0; kk < 4; kk++) {
        int k0 = kk * 128;
#pragma unroll
        for (int i2 = 0; i2 < 4; i2++) {
            int r = i2 * 32 + s_r;
            int slot = (i2 * 256 + t) * 16;
            load_lds16(A + (size_t)(ibase + r) * DIM + k0 + s_c * 16, As + slot);
            load_lds16(A + (size_t)(jbase + r) * DIM + k0 + s_c * 16, Bs + slot);
        }
        __syncthreads();

        // fragments: lane holds X[m=lm][k = q*32 .. q*32+31] => logical chunks 2q, 2q+1
        intx8 bfv[4];
#pragma unroll
        for (int tn = 0; tn < 4; tn++) {
            int R = wn * 64 + tn * 16 + lm;
            const int4* rowp = (const int4*)(Bs + R * 128);
            int4 lo = rowp[(2 * q) ^ (R & 7)];
            int4 hi = rowp[(2 * q + 1) ^ (R & 7)];
            intx8 v;
            v[0] = lo.x; v[1] = lo.y; v[2] = lo.z; v[3] = lo.w;
            v[4] = hi.x; v[5] = hi.y; v[6] = hi.z; v[7] = hi.w;
            bfv[tn] = v;
        }
#pragma unroll
        for (int tm = 0; tm < 4; tm++) {
            int R = wm * 64 + tm * 16 + lm;
            const int4* rowp = (const int4*)(As + R * 128);
            int4 lo = rowp[(2 * q) ^ (R & 7)];
            int4 hi = rowp[(2 * q + 1) ^ (R & 7)];
            intx8 af;
            af[0] = lo.x; af[1] = lo.y; af[2] = lo.z; af[3] = lo.w;
            af[4] = hi.x; af[5] = hi.y; af[6] = hi.z; af[7] = hi.w;
#pragma unroll
            for (int tn = 0; tn < 4; tn++)
                acc[tm][tn] = __builtin_amdgcn_mfma_scale_f32_16x16x128_f8f6f4(
                    af, bfv[tn], acc[tm][tn], 0, 0,      // cbsz=fp8, blgp=fp8
                    0, 0x7F7F7F7F,                        // scale A = 1.0 (any byte)
                    0, 0x7F7F7F7F);                       // scale B = 1.0
        }
        __syncthreads();
    }

    // C/D layout: col = lane&15, row = (lane>>4)*4 + reg [m89/m91; shape-determined]
    const float INF = __builtin_inff();

    if (!diag) {
        // ---- max-only epilogue (no labels) ----
        float mxJ[4];
#pragma unroll
        for (int tn = 0; tn < 4; tn++) mxJ[tn] = -INF;
#pragma unroll
        for (int tm = 0; tm < 4; tm++) {
#pragma unroll
            for (int r = 0; r < 4; r++) {
                int row_l = wm * 64 + tm * 16 + q * 4 + r;
                float mxI = -INF;
#pragma unroll
                for (int tn = 0; tn < 4; tn++) {
                    float v = acc[tm][tn][r];
                    mxI = fmaxf(mxI, v);
                    mxJ[tn] = fmaxf(mxJ[tn], v);
                }
#pragma unroll
                for (int s = 1; s < 16; s <<= 1)
                    mxI = fmaxf(mxI, __shfl_xor(mxI, s, 64));
                if (lm == 0) redA[row_l][wn] = mxI;
            }
        }
#pragma unroll
        for (int tn = 0; tn < 4; tn++) {
#pragma unroll
            for (int s = 16; s < 64; s <<= 1)
                mxJ[tn] = fmaxf(mxJ[tn], __shfl_xor(mxJ[tn], s, 64));
            if (q == 0) redB[wn * 64 + tn * 16 + lm][wm] = mxJ[tn];
        }
        __syncthreads();
        if (t < 128) {
            atomicMax(&maxEnc[ibase + t], enc_f(fmaxf(redA[t][0], redA[t][1])));
            atomicMax(&maxEnc[jbase + t], enc_f(fmaxf(redB[t][0], redB[t][1])));
        }
    } else {
        // ---- mixed epilogue (min-same / max-diff); extra LDS aliases dead As ----
        int* labi = (int*)As;                             // 512 B
        int* labj = labi + 128;                           // 512 B
        float (*redImn)[2] = (float (*)[2])(labj + 128);  // 1 KB
        float (*redJmn)[2] = redImn + 128;                // 1 KB
        if (t < 128) labi[t] = sortedLabel[ibase + t];
        else labj[t - 128] = sortedLabel[jbase + t - 128];
        __syncthreads();

        int jlab[4];
#pragma unroll
        for (int tn = 0; tn < 4; tn++) jlab[tn] = labj[wn * 64 + tn * 16 + lm];

        float mnJ[4], mxJ[4];
#pragma unroll
        for (int tn = 0; tn < 4; tn++) { mnJ[tn] = INF; mxJ[tn] = -INF; }

#pragma unroll
        for (int tm = 0; tm < 4; tm++) {
#pragma unroll
            for (int r = 0; r < 4; r++) {
                int row_l = wm * 64 + tm * 16 + q * 4 + r;
                int il = labi[row_l];
                float mnI = INF, mxI = -INF;
#pragma unroll
                for (int tn = 0; tn < 4; tn++) {
                    float v = acc[tm][tn][r];
                    bool same = (jlab[tn] == il);
                    float vs = same ? v : INF;
                    float vd = same ? -INF : v;
                    mnI = fminf(mnI, vs);
                    mxI = fmaxf(mxI, vd);
                    mnJ[tn] = fminf(mnJ[tn], vs);
                    mxJ[tn] = fmaxf(mxJ[tn], vd);
                }
#pragma unroll
                for (int s = 1; s < 16; s <<= 1) {
                    mnI = fminf(mnI, __shfl_xor(mnI, s, 64));
                    mxI = fmaxf(mxI, __shfl_xor(mxI, s, 64));
                }
                if (lm == 0) { redImn[row_l][wn] = mnI; redA[row_l][wn] = mxI; }
            }
        }
#pragma unroll
        for (int tn = 0; tn < 4; tn++) {
#pragma unroll
            for (int s = 16; s < 64; s <<= 1) {
                mnJ[tn] = fminf(mnJ[tn], __shfl_xor(mnJ[tn], s, 64));
                mxJ[tn] = fmaxf(mxJ[tn], __shfl_xor(mxJ[tn], s, 64));
            }
            if (q == 0) {
                int col_l = wn * 64 + tn * 16 + lm;
                redJmn[col_l][wm] = mnJ[tn];
                redB[col_l][wm] = mxJ[tn];
            }
        }
        __syncthreads();
        if (t < 128) {
            atomicMin(&minEnc[ibase + t], enc_f(fminf(redImn[t][0], redImn[t][1])));
            atomicMax(&maxEnc[ibase + t], enc_f(fmaxf(redA[t][0], redA[t][1])));
            atomicMin(&minEnc[jbase + t], enc_f(fminf(redJmn[t][0], redJmn[t][1])));
            atomicMax(&maxEnc[jbase + t], enc_f(fmaxf(redB[t][0], redB[t][1])));
        }
    }
}

// 32 blocks; one float atomicAdd per block into pre-zeroed out[0].
__global__ __launch_bounds__(256) void finalize_kernel(const unsigned* __restrict__ minEnc,
                                                       const unsigned* __restrict__ maxEnc,
                                                       const float* __restrict__ cePartial,
                                                       float* __restrict__ out) {
    int gid = blockIdx.x * 256 + threadIdx.x;   // 8192 threads total
    float mn = dec_f(minEnc[gid]);
    float mxv = dec_f(maxEnc[gid]);
    // pos - neg = 2*(max_diff G - min_same G); sq_i cancels, sq_j ≈ 1 (dev ~1e-7)
    float s = fmaxf(2.0f * (mxv - mn) + MARGIN_F, 0.f);
    if (gid < ROWSTAT_BLOCKS) s += cePartial[gid];
#pragma unroll
    for (int sh = 1; sh < 64; sh <<= 1) s += __shfl_xor(s, sh, 64);
    __shared__ float red[4];
    int w = threadIdx.x >> 6, l = threadIdx.x & 63;
    if (l == 0) red[w] = s;
    __syncthreads();
    if (threadIdx.x == 0)
        atomicAdd(out, (red[0] + red[1] + red[2] + red[3]) * (1.0f / (float)N_ROWS));
}

extern "C" void kernel_launch(void* const* d_in, const int* in_sizes, int n_in,
                              void* d_out, int out_size, void* d_ws, size_t ws_size,
                              hipStream_t stream) {
    const float* x = (const float*)d_in[0];
    const int* label = (const int*)d_in[1];
    float* out = (float*)d_out;

    char* ws = (char*)d_ws;
    unsigned char* a8 = (unsigned char*)ws;                      // 4 MB fp8 sorted copy
    char* p = ws + (size_t)N_ROWS * DIM;
    unsigned* minEnc = (unsigned*)p;            p += N_ROWS * 4;
    unsigned* maxEnc = (unsigned*)p;            p += N_ROWS * 4;
    float* cePartial = (float*)p;               p += ROWSTAT_BLOCKS * 4;
    int* offsetArr = (int*)p;                   p += NLAB * 4;
    int* cnt = (int*)p;                         p += NLAB * 4;
    int* sortedLabel = (int*)p;                 p += N_ROWS * 4;

    histscan_kernel<<<1, 512, 0, stream>>>(label, offsetArr, cnt, out);
    rowstats_kernel<<<ROWSTAT_BLOCKS, 256, 0, stream>>>(x, label, offsetArr, cnt, a8,
                                                        sortedLabel, cePartial, minEnc, maxEnc);
    gemm_kernel<<<NTILE, 256, 0, stream>>>(a8, sortedLabel, minEnc, maxEnc);
    finalize_kernel<<<32, 256, 0, stream>>>(minEnc, maxEnc, cePartial, out);
}